// Round 1
// baseline (10163.462 us; speedup 1.0000x reference)
//
#include <hip/hip_runtime.h>

// ---------------- problem constants ----------------
#define Bz   2
#define Tz   1024
#define Dz   768
#define Hz   12
#define HDz  64
#define Lz   8
#define Vz   32000
#define BTz  (Bz*Tz)       // 2048
#define DFz  (4*Dz)        // 3072
#define SCALEz 0.036084391824351615f  // 768^-0.5  (reference uses D^-0.5, not HD^-0.5)

typedef __attribute__((ext_vector_type(4))) short s16x4;
typedef __attribute__((ext_vector_type(8))) short s16x8;
typedef __attribute__((ext_vector_type(4))) float f32x4;

__device__ __forceinline__ short f2b(float f) {  // f32 -> bf16 (RNE)
    union { float f; unsigned u; } uv; uv.f = f;
    unsigned r = uv.u + 0x7fffu + ((uv.u >> 16) & 1u);
    return (short)(r >> 16);
}

// ---------------- generic bf16 MFMA GEMM ----------------
// C[M,N] = epilogue( A[M,K] @ B[K,N] ), f32 in/out, bf16 internal, f32 accum.
// BTRANS: B physically stored [N,K] row-major (used for Q·K^T).
// EPI: 0 none | 1 +bias | 2 +bias+res | 3 +bias,GELU | 4 *scale,causal mask
// batching: z -> ( (z/Hb)*s?b + (z%Hb)*s?h ) element offsets.
template<int BM, int BN, int WM, int WN, bool BTRANS, int EPI>
__global__ __launch_bounds__(WM*WN*64)
void gemm_k(const float* __restrict__ A, const float* __restrict__ B,
            const float* __restrict__ bias, const float* __restrict__ res,
            float* __restrict__ C,
            int M, int N, int K, int lda, int ldb, int ldc,
            int Hb, long sAb, long sAh, long sBb, long sBh, long sCb, long sCh,
            float scale)
{
    constexpr int BK = 32;
    constexpr int SA = 40;                 // padded LDS stride (elements)
    constexpr int THREADS = WM*WN*64;
    constexpr int WTM = BM/WM, WTN = BN/WN;
    constexpr int AM = WTM/16, BNF = WTN/16;

    __shared__ short Al[BM*SA];
    __shared__ short Bl[BN*SA];

    const int z = blockIdx.z;
    A += (long)(z / Hb) * sAb + (long)(z % Hb) * sAh;
    B += (long)(z / Hb) * sBb + (long)(z % Hb) * sBh;
    C += (long)(z / Hb) * sCb + (long)(z % Hb) * sCh;
    if (res) res += (long)(z / Hb) * sCb + (long)(z % Hb) * sCh;

    const int m0 = blockIdx.y * BM;
    const int n0 = blockIdx.x * BN;
    const int tid  = threadIdx.x;
    const int lane = tid & 63, wid = tid >> 6;
    const int wm = wid / WN, wn = wid % WN;
    const int r  = lane & 15, kg = lane >> 4;

    f32x4 acc[AM][BNF] = {};

    for (int k0 = 0; k0 < K; k0 += BK) {
        // ---- stage A tile (BM x BK) as bf16 ----
        for (int qi = tid; qi < BM*(BK/4); qi += THREADS) {
            int row = qi >> 3;            // BK/4 == 8
            int kq  = (qi & 7) << 2;
            const float4 f = *reinterpret_cast<const float4*>(A + (long)(m0+row)*lda + (k0+kq));
            s16x4 v4 = { f2b(f.x), f2b(f.y), f2b(f.z), f2b(f.w) };
            *reinterpret_cast<s16x4*>(&Al[row*SA + kq]) = v4;
        }
        // ---- stage B tile transposed: Bl[n][k] ----
        if constexpr (BTRANS) {
            for (int qi = tid; qi < BN*(BK/4); qi += THREADS) {
                int row = qi >> 3;
                int kq  = (qi & 7) << 2;
                const float4 f = *reinterpret_cast<const float4*>(B + (long)(n0+row)*ldb + (k0+kq));
                s16x4 v4 = { f2b(f.x), f2b(f.y), f2b(f.z), f2b(f.w) };
                *reinterpret_cast<s16x4*>(&Bl[row*SA + kq]) = v4;
            }
        } else {
            for (int qi = tid; qi < BK*(BN/4); qi += THREADS) {
                int kk = qi / (BN/4);
                int nq = (qi % (BN/4)) * 4;
                const float4 f = *reinterpret_cast<const float4*>(B + (long)(k0+kk)*ldb + (n0+nq));
                Bl[(nq+0)*SA + kk] = f2b(f.x);
                Bl[(nq+1)*SA + kk] = f2b(f.y);
                Bl[(nq+2)*SA + kk] = f2b(f.z);
                Bl[(nq+3)*SA + kk] = f2b(f.w);
            }
        }
        __syncthreads();

        // ---- MFMA: fragment k = kg*8 + j, A row / B col = r ----
        s16x8 af[AM], bfr[BNF];
        #pragma unroll
        for (int m = 0; m < AM; m++)
            af[m] = *reinterpret_cast<const s16x8*>(&Al[(wm*WTM + m*16 + r)*SA + kg*8]);
        #pragma unroll
        for (int n = 0; n < BNF; n++)
            bfr[n] = *reinterpret_cast<const s16x8*>(&Bl[(wn*WTN + n*16 + r)*SA + kg*8]);
        #pragma unroll
        for (int m = 0; m < AM; m++)
            #pragma unroll
            for (int n = 0; n < BNF; n++)
                acc[m][n] = __builtin_amdgcn_mfma_f32_16x16x32_bf16(af[m], bfr[n], acc[m][n], 0, 0, 0);
        __syncthreads();
    }

    // ---- epilogue: C/D layout col=lane&15, row=(lane>>4)*4+reg ----
    #pragma unroll
    for (int m = 0; m < AM; m++) {
        #pragma unroll
        for (int n = 0; n < BNF; n++) {
            #pragma unroll
            for (int reg = 0; reg < 4; reg++) {
                int row = wm*WTM + m*16 + kg*4 + reg;
                int col = wn*WTN + n*16 + r;
                int gr = m0 + row, gc = n0 + col;
                float v = acc[m][n][reg];
                if constexpr (EPI == 1 || EPI == 2 || EPI == 3) v += bias[gc];
                if constexpr (EPI == 2) v += res[(long)gr*ldc + gc];
                if constexpr (EPI == 3) v = 0.5f*v*(1.0f + erff(v*0.70710678118654752f));
                if constexpr (EPI == 4) { v *= scale; if (gc > gr) v = -1e30f; }
                C[(long)gr*ldc + gc] = v;
            }
        }
    }
}

// ---------------- embedding: x = tok_emb[idx] + pos_emb ----------------
__global__ void embed_k(const int* __restrict__ idx, const float* __restrict__ tok,
                        const float* __restrict__ pos, float* __restrict__ x)
{
    int qi = blockIdx.x*blockDim.x + threadIdx.x;     // BT * (D/4) quads
    if (qi >= BTz*(Dz/4)) return;
    int row = qi / (Dz/4);
    int c   = (qi % (Dz/4)) * 4;
    int token = idx[row];
    int tpos  = row & (Tz-1);
    float4 a = *reinterpret_cast<const float4*>(tok + (long)token*Dz + c);
    float4 p = *reinterpret_cast<const float4*>(pos + (long)tpos*Dz + c);
    float4 o; o.x=a.x+p.x; o.y=a.y+p.y; o.z=a.z+p.z; o.w=a.w+p.w;
    *reinterpret_cast<float4*>(x + (long)row*Dz + c) = o;
}

// ---------------- layernorm over D=768, block 256 per row ----------------
__global__ void ln_k(const float* __restrict__ x, const float* __restrict__ w,
                     const float* __restrict__ b, float* __restrict__ y)
{
    int row = blockIdx.x;
    const float* xr = x + (long)row*Dz;
    int t = threadIdx.x;
    float v0 = xr[t], v1 = xr[t+256], v2 = xr[t+512];
    __shared__ float s1[256], s2[256];
    s1[t] = v0+v1+v2;
    s2[t] = v0*v0+v1*v1+v2*v2;
    __syncthreads();
    for (int k = 128; k > 0; k >>= 1) {
        if (t < k) { s1[t] += s1[t+k]; s2[t] += s2[t+k]; }
        __syncthreads();
    }
    float mean = s1[0] * (1.0f/Dz);
    float var  = s2[0] * (1.0f/Dz) - mean*mean;
    float rs = rsqrtf(var + 1e-5f);
    float* yr = y + (long)row*Dz;
    yr[t]     = (v0-mean)*rs*w[t]     + b[t];
    yr[t+256] = (v1-mean)*rs*w[t+256] + b[t+256];
    yr[t+512] = (v2-mean)*rs*w[t+512] + b[t+512];
}

// ---------------- row softmax over T=1024 (scores, in place) ----------------
__global__ void softmax_k(float* __restrict__ S)
{
    long row = blockIdx.x;
    float* sr = S + row * Tz;
    int t = threadIdx.x;
    float v[4];
    #pragma unroll
    for (int j = 0; j < 4; j++) v[j] = sr[t + j*256];
    float mx = fmaxf(fmaxf(v[0],v[1]), fmaxf(v[2],v[3]));
    __shared__ float sm[256];
    sm[t] = mx; __syncthreads();
    for (int k = 128; k > 0; k >>= 1) { if (t < k) sm[t] = fmaxf(sm[t], sm[t+k]); __syncthreads(); }
    float m = sm[0]; __syncthreads();
    float s = 0.f;
    #pragma unroll
    for (int j = 0; j < 4; j++) { v[j] = expf(v[j]-m); s += v[j]; }
    sm[t] = s; __syncthreads();
    for (int k = 128; k > 0; k >>= 1) { if (t < k) sm[t] += sm[t+k]; __syncthreads(); }
    float inv = 1.0f / sm[0];
    #pragma unroll
    for (int j = 0; j < 4; j++) sr[t + j*256] = v[j]*inv;
}

// ---------------- per-row log-softmax loss over V=32000 ----------------
__global__ void loss_rows_k(const float* __restrict__ logits, const int* __restrict__ tgt,
                            float* __restrict__ row_loss)
{
    int row = blockIdx.x;
    const float* lr = logits + (long)row*Vz;
    int t = threadIdx.x;
    __shared__ float sm[256];
    float mx = -3.4e38f;
    for (int c = t; c < Vz; c += 256) mx = fmaxf(mx, lr[c]);
    sm[t] = mx; __syncthreads();
    for (int k = 128; k > 0; k >>= 1) { if (t < k) sm[t] = fmaxf(sm[t], sm[t+k]); __syncthreads(); }
    float m = sm[0]; __syncthreads();
    float s = 0.f;
    for (int c = t; c < Vz; c += 256) s += expf(lr[c]-m);
    sm[t] = s; __syncthreads();
    for (int k = 128; k > 0; k >>= 1) { if (t < k) sm[t] += sm[t+k]; __syncthreads(); }
    if (t == 0) {
        float logZ = m + logf(sm[0]);
        row_loss[row] = logZ - lr[tgt[row]];
    }
}

__global__ void loss_reduce_k(const float* __restrict__ row_loss, float* __restrict__ out)
{
    __shared__ float sm[256];
    int t = threadIdx.x;
    float s = 0.f;
    for (int i = t; i < BTz; i += 256) s += row_loss[i];
    sm[t] = s; __syncthreads();
    for (int k = 128; k > 0; k >>= 1) { if (t < k) sm[t] += sm[t+k]; __syncthreads(); }
    if (t == 0) out[0] = sm[0] * (1.0f/BTz);
}

// ---------------- host ----------------
extern "C" void kernel_launch(void* const* d_in, const int* in_sizes, int n_in,
                              void* d_out, int out_size, void* d_ws, size_t ws_size,
                              hipStream_t stream)
{
    const int*   idx     = (const int*)  d_in[0];
    const int*   tgt     = (const int*)  d_in[1];
    const float* tok_emb = (const float*)d_in[2];
    const float* pos_emb = (const float*)d_in[3];
    const float* ln1_w   = (const float*)d_in[4];
    const float* ln1_b   = (const float*)d_in[5];
    const float* wq      = (const float*)d_in[6];
    const float* wk      = (const float*)d_in[7];
    const float* wv      = (const float*)d_in[8];
    const float* wo      = (const float*)d_in[9];
    const float* bo      = (const float*)d_in[10];
    const float* ln2_w   = (const float*)d_in[11];
    const float* ln2_b   = (const float*)d_in[12];
    const float* w1      = (const float*)d_in[13];
    const float* b1      = (const float*)d_in[14];
    const float* w2      = (const float*)d_in[15];
    const float* b2      = (const float*)d_in[16];
    const float* lnf_w   = (const float*)d_in[17];
    const float* lnf_b   = (const float*)d_in[18];
    const float* lm_w    = (const float*)d_in[19];
    const float* lm_b    = (const float*)d_in[20];

    float* logits = (float*)d_out;
    float* loss   = logits + (long)BTz*Vz;

    float* ws = (float*)d_ws;
    float* x      = ws; ws += (long)BTz*Dz;
    float* h      = ws; ws += (long)BTz*Dz;
    float* q      = ws; ws += (long)BTz*Dz;
    float* kk     = ws; ws += (long)BTz*Dz;
    float* vv     = ws; ws += (long)BTz*Dz;
    float* attn   = ws; ws += (long)BTz*Dz;
    float* mid    = ws; ws += (long)BTz*DFz;
    float* rloss  = ws; ws += BTz;
    float* scores = ws;
    long base_floats = 6L*BTz*Dz + (long)BTz*DFz + BTz;
    long score_cap = (long)(ws_size/sizeof(float)) - base_floats;
    int hg = (int)(score_cap / ((long)Tz*Tz));   // heads of scores that fit at once
    if (hg > Hz) hg = Hz;
    if (hg < 1)  hg = 1;

    embed_k<<<dim3((BTz*(Dz/4) + 255)/256), 256, 0, stream>>>(idx, tok_emb, pos_emb, x);

    for (int l = 0; l < Lz; l++) {
        ln_k<<<BTz, 256, 0, stream>>>(x, ln1_w + l*Dz, ln1_b + l*Dz, h);
        // q,k,v projections (no bias)
        gemm_k<128,128,2,2,false,0><<<dim3(Dz/128, BTz/128, 1), 256, 0, stream>>>(
            h, wq + (long)l*Dz*Dz, nullptr, nullptr, q,  BTz, Dz, Dz, Dz, Dz, Dz,
            1, 0,0, 0,0, 0,0, 0.f);
        gemm_k<128,128,2,2,false,0><<<dim3(Dz/128, BTz/128, 1), 256, 0, stream>>>(
            h, wk + (long)l*Dz*Dz, nullptr, nullptr, kk, BTz, Dz, Dz, Dz, Dz, Dz,
            1, 0,0, 0,0, 0,0, 0.f);
        gemm_k<128,128,2,2,false,0><<<dim3(Dz/128, BTz/128, 1), 256, 0, stream>>>(
            h, wv + (long)l*Dz*Dz, nullptr, nullptr, vv, BTz, Dz, Dz, Dz, Dz, Dz,
            1, 0,0, 0,0, 0,0, 0.f);
        // attention, chunked over (batch, head-group) to fit ws
        for (int b = 0; b < Bz; b++) {
            for (int g0 = 0; g0 < Hz; g0 += hg) {
                int gz = (Hz - g0 < hg) ? (Hz - g0) : hg;
                const float* qb = q    + (long)b*Tz*Dz + g0*HDz;
                const float* kb = kk   + (long)b*Tz*Dz + g0*HDz;
                const float* vb = vv   + (long)b*Tz*Dz + g0*HDz;
                float*       ab = attn + (long)b*Tz*Dz + g0*HDz;
                // S = scale * q k^T with causal mask  (B operand physically [T,HD])
                gemm_k<128,128,2,2,true,4><<<dim3(Tz/128, Tz/128, gz), 256, 0, stream>>>(
                    qb, kb, nullptr, nullptr, scores, Tz, Tz, HDz, Dz, Dz, Tz,
                    gz, 0,(long)HDz, 0,(long)HDz, 0,(long)Tz*Tz, SCALEz);
                softmax_k<<<gz*Tz, 256, 0, stream>>>(scores);
                // O = P @ V
                gemm_k<128,64,2,1,false,0><<<dim3(1, Tz/128, gz), 128, 0, stream>>>(
                    scores, vb, nullptr, nullptr, ab, Tz, HDz, Tz, Tz, Dz, Dz,
                    gz, 0,(long)Tz*Tz, 0,(long)HDz, 0,(long)HDz, 0.f);
            }
        }
        // x = x + attn @ Wo + Bo   (in-place residual)
        gemm_k<128,128,2,2,false,2><<<dim3(Dz/128, BTz/128, 1), 256, 0, stream>>>(
            attn, wo + (long)l*Dz*Dz, bo + l*Dz, x, x, BTz, Dz, Dz, Dz, Dz, Dz,
            1, 0,0, 0,0, 0,0, 0.f);
        ln_k<<<BTz, 256, 0, stream>>>(x, ln2_w + l*Dz, ln2_b + l*Dz, h);
        // mid = gelu(h @ W1 + B1)
        gemm_k<128,128,2,2,false,3><<<dim3(DFz/128, BTz/128, 1), 256, 0, stream>>>(
            h, w1 + (long)l*Dz*DFz, b1 + l*DFz, nullptr, mid, BTz, DFz, Dz, Dz, DFz, DFz,
            1, 0,0, 0,0, 0,0, 0.f);
        // x = x + mid @ W2 + B2
        gemm_k<128,128,2,2,false,2><<<dim3(Dz/128, BTz/128, 1), 256, 0, stream>>>(
            mid, w2 + (long)l*DFz*Dz, b2 + l*Dz, x, x, BTz, Dz, DFz, DFz, Dz, Dz,
            1, 0,0, 0,0, 0,0, 0.f);
    }

    ln_k<<<BTz, 256, 0, stream>>>(x, lnf_w, lnf_b, h);
    // logits = h @ lm_w + lm_b
    gemm_k<128,128,2,2,false,1><<<dim3(Vz/128, BTz/128, 1), 256, 0, stream>>>(
        h, lm_w, lm_b, nullptr, logits, BTz, Vz, Dz, Dz, Vz, Vz,
        1, 0,0, 0,0, 0,0, 0.f);

    loss_rows_k<<<BTz, 256, 0, stream>>>(logits, tgt, rloss);
    loss_reduce_k<<<1, 256, 0, stream>>>(rloss, loss);
}

// Round 3
// 1877.780 us; speedup vs baseline: 5.4125x; 5.4125x over previous
//
#include <hip/hip_runtime.h>

#define Bz   2
#define Tz   1024
#define Dz   768
#define Hz   12
#define HDz  64
#define Lz   8
#define Vz   32000
#define BTz  (Bz*Tz)       // 2048
#define DFz  (4*Dz)        // 3072
#define SCALEz 0.036084391824351615f  // 768^-0.5 (reference uses D^-0.5)

typedef __attribute__((ext_vector_type(4))) short s16x4;
typedef __attribute__((ext_vector_type(8))) short s16x8;
typedef __attribute__((ext_vector_type(4))) float f32x4;

__device__ __forceinline__ short f2b(float f) {  // f32 -> bf16 RNE
    union { float f; unsigned u; } v; v.f = f;
    unsigned r = v.u + 0x7fffu + ((v.u >> 16) & 1u);
    return (short)(r >> 16);
}

__device__ __forceinline__ void gload16(const short* g, short* l) {
    __builtin_amdgcn_global_load_lds(
        (const __attribute__((address_space(1))) void*)g,
        (__attribute__((address_space(3))) void*)l, 16, 0, 0);
}

#define MFMA32(a,b,c) __builtin_amdgcn_mfma_f32_16x16x32_bf16(a,b,c,0,0,0)

// ---------------- transpose-convert: f32 [K][N](ldin) -> bf16 [N][K] ----------------
__global__ __launch_bounds__(256)
void tconv_k(const float* __restrict__ in, short* __restrict__ out,
             int K, int N, int ldin)
{
    __shared__ float tl[32][33];
    const int tx = threadIdx.x & 31, ty = threadIdx.x >> 5;
    const int n0 = blockIdx.x * 32, k0 = blockIdx.y * 32;
    #pragma unroll
    for (int i = 0; i < 4; i++)
        tl[ty + i*8][tx] = in[(long)(k0 + ty + i*8)*ldin + n0 + tx];
    __syncthreads();
    #pragma unroll
    for (int i = 0; i < 4; i++)
        out[(long)(n0 + ty + i*8)*K + k0 + tx] = f2b(tl[tx][ty + i*8]);
}

// ---------------- generic bf16 GEMM, m97-structure ----------------
// C[M,N] = epi( A[M,K] @ Bt[N,K]^T ). A,Bt bf16 row-major K-contiguous.
// EPI: 0 none | 1 +bias | 2 +bias+res(f32) | 3 +bias,GELU(exact)
template<int BM, int EPI, bool OUTBF>
__global__ __launch_bounds__(256)
void gemm2(const short* __restrict__ A, const short* __restrict__ Bt,
           const float* __restrict__ bias, const float* __restrict__ resp,
           void* __restrict__ Cv, int K, int ldc)
{
    constexpr int BN = 128, BK = 64;
    constexpr int WTM = BM/2;
    constexpr int AM = WTM/16;
    __shared__ short Al[BM*BK];
    __shared__ short Bl[BN*BK];
    const int m0 = blockIdx.y*BM, n0 = blockIdx.x*BN;
    const int tid = threadIdx.x, lane = tid & 63, wid = tid >> 6;
    const int wm = wid >> 1, wn = wid & 1;
    const int r = lane & 15, kg = lane >> 4;
    const int arow = lane >> 3, acol = (lane & 7)*8;

    const short* ga = A  + (long)(m0 + wid*(BM/4) + arow)*K + acol;
    const short* gb = Bt + (long)(n0 + wid*32     + arow)*K + acol;
    short* la = &Al[(wid*(BM/4))*BK];
    short* lb = &Bl[(wid*32)*BK];

    f32x4 acc[AM][4] = {};

    for (int k0 = 0; k0 < K; k0 += BK) {
        #pragma unroll
        for (int i = 0; i < BM/32; i++)
            gload16(ga + (long)i*8*K + k0, la + i*8*BK);
        #pragma unroll
        for (int i = 0; i < 4; i++)
            gload16(gb + (long)i*8*K + k0, lb + i*8*BK);
        __syncthreads();
        #pragma unroll
        for (int ks = 0; ks < 2; ks++) {
            s16x8 af[AM], bf[4];
            #pragma unroll
            for (int mI = 0; mI < AM; mI++)
                af[mI] = *(const s16x8*)&Al[(wm*WTM + mI*16 + r)*BK + ks*32 + kg*8];
            #pragma unroll
            for (int nI = 0; nI < 4; nI++)
                bf[nI] = *(const s16x8*)&Bl[(wn*64 + nI*16 + r)*BK + ks*32 + kg*8];
            #pragma unroll
            for (int mI = 0; mI < AM; mI++)
                #pragma unroll
                for (int nI = 0; nI < 4; nI++)
                    acc[mI][nI] = MFMA32(af[mI], bf[nI], acc[mI][nI]);
        }
        __syncthreads();
    }

    #pragma unroll
    for (int mI = 0; mI < AM; mI++) {
        #pragma unroll
        for (int nI = 0; nI < 4; nI++) {
            #pragma unroll
            for (int reg = 0; reg < 4; reg++) {
                int row = wm*WTM + mI*16 + kg*4 + reg;
                int col = wn*64 + nI*16 + r;
                long off = (long)(m0+row)*ldc + (n0+col);
                float v = acc[mI][nI][reg];
                if constexpr (EPI >= 1) v += bias[n0+col];
                if constexpr (EPI == 2) v += resp[off];
                if constexpr (EPI == 3) v = 0.5f*v*(1.0f + erff(v*0.70710678118654752f));
                if constexpr (OUTBF) ((short*)Cv)[off] = f2b(v);
                else                 ((float*)Cv)[off] = v;
            }
        }
    }
}

// ---------------- fused flash attention ----------------
// qkv: bf16 [B*T][2304] (q|k|v each 768, head h at col h*64). att: bf16 [B*T][768].
// One wave = 16 q rows; swapped QK^T (S^T), online softmax.
// PV uses mfma 16x16x32 with the upper k-half zero-padded (B=0 there => exact).
__global__ __launch_bounds__(256)
void attn_k(const short* __restrict__ qkv, short* __restrict__ att)
{
    const int w = threadIdx.x >> 6;
    const int lane = threadIdx.x & 63;
    const int r = lane & 15, kg = lane >> 4;
    const int hd0 = blockIdx.y * HDz;
    const long brow = (long)blockIdx.z * Tz;
    const int q0w = blockIdx.x * 64 + w * 16;
    const int qi = q0w + r;

    const short* qp = qkv + (brow + q0w + r) * 2304 + hd0;
    const s16x8 qf0 = *(const s16x8*)(qp + kg*8);
    const s16x8 qf1 = *(const s16x8*)(qp + 32 + kg*8);
    const short* kb = qkv + brow * 2304 + 768 + hd0;
    const short* vb = qkv + brow * 2304 + 1536 + hd0;

    float m = -3.4e38f, l = 0.f;
    f32x4 ot[4] = {};

    const int ntiles = blockIdx.x * 4 + w + 1;
    for (int t = 0; t < ntiles; t++) {
        const int kt = t * 16;
        const short* kp = kb + (long)(kt + r) * 2304;
        s16x8 kf0 = *(const s16x8*)(kp + kg*8);
        s16x8 kf1 = *(const s16x8*)(kp + 32 + kg*8);
        f32x4 z = {};
        f32x4 st = MFMA32(kf0, qf0, z);   // S^T: row=key kt+kg*4+reg, col=q q0w+r
        st = MFMA32(kf1, qf1, st);
        float s4[4];
        #pragma unroll
        for (int j = 0; j < 4; j++) {
            int ki = kt + kg*4 + j;
            s4[j] = (ki <= qi) ? st[j]*SCALEz : -1e30f;
        }
        float cm = fmaxf(fmaxf(s4[0], s4[1]), fmaxf(s4[2], s4[3]));
        cm = fmaxf(cm, __shfl_xor(cm, 16));
        cm = fmaxf(cm, __shfl_xor(cm, 32));
        float mn = fmaxf(m, cm);
        float alpha = __expf(m - mn);
        float p0 = __expf(s4[0]-mn), p1 = __expf(s4[1]-mn);
        float p2 = __expf(s4[2]-mn), p3 = __expf(s4[3]-mn);
        l = l*alpha + (p0+p1+p2+p3);
        m = mn;
        // B-frag (P): k = kg*8+j -> key kt+kg*4+j for j<4, zero-pad j>=4
        s16x8 pb = { f2b(p0), f2b(p1), f2b(p2), f2b(p3), 0, 0, 0, 0 };
        #pragma unroll
        for (int d0 = 0; d0 < 4; d0++) {
            const short* vp = vb + (long)(kt + kg*4)*2304 + d0*16 + r;
            // A-frag (V^T): row d=r, k=kg*8+j -> V[kt+kg*4+j][d0*16+r] for j<4, pad 0
            s16x8 va = { vp[0], vp[2304], vp[4608], vp[6912], 0, 0, 0, 0 };
            f32x4 o = ot[d0];
            o[0]*=alpha; o[1]*=alpha; o[2]*=alpha; o[3]*=alpha;
            ot[d0] = MFMA32(va, pb, o);   // O^T: row d=kg*4+reg, col q=r
        }
    }
    l += __shfl_xor(l, 16);
    l += __shfl_xor(l, 32);
    const float inv = 1.f / l;
    short* ap = att + (brow + q0w + r)*Dz + hd0;
    #pragma unroll
    for (int d0 = 0; d0 < 4; d0++)
        #pragma unroll
        for (int j = 0; j < 4; j++)
            ap[d0*16 + kg*4 + j] = f2b(ot[d0][j]*inv);
}

// ---------------- embedding: x = tok_emb[idx] + pos_emb (f32) ----------------
__global__ void embed_k(const int* __restrict__ idx, const float* __restrict__ tok,
                        const float* __restrict__ pos, float* __restrict__ x)
{
    int qi = blockIdx.x*blockDim.x + threadIdx.x;
    if (qi >= BTz*(Dz/4)) return;
    int row = qi / (Dz/4);
    int c   = (qi % (Dz/4)) * 4;
    int token = idx[row];
    int tpos  = row & (Tz-1);
    float4 a = *reinterpret_cast<const float4*>(tok + (long)token*Dz + c);
    float4 p = *reinterpret_cast<const float4*>(pos + (long)tpos*Dz + c);
    float4 o; o.x=a.x+p.x; o.y=a.y+p.y; o.z=a.z+p.z; o.w=a.w+p.w;
    *reinterpret_cast<float4*>(x + (long)row*Dz + c) = o;
}

// ---------------- layernorm: f32 in, bf16 out ----------------
__global__ __launch_bounds__(256)
void ln_k(const float* __restrict__ x, const float* __restrict__ w,
          const float* __restrict__ b, short* __restrict__ y)
{
    int row = blockIdx.x;
    const float* xr = x + (long)row*Dz;
    int t = threadIdx.x;
    float v0 = xr[t], v1 = xr[t+256], v2 = xr[t+512];
    __shared__ float s1[256], s2[256];
    s1[t] = v0+v1+v2;
    s2[t] = v0*v0+v1*v1+v2*v2;
    __syncthreads();
    for (int k = 128; k > 0; k >>= 1) {
        if (t < k) { s1[t] += s1[t+k]; s2[t] += s2[t+k]; }
        __syncthreads();
    }
    float mean = s1[0] * (1.0f/Dz);
    float var  = s2[0] * (1.0f/Dz) - mean*mean;
    float rs = rsqrtf(var + 1e-5f);
    short* yr = y + (long)row*Dz;
    yr[t]     = f2b((v0-mean)*rs*w[t]     + b[t]);
    yr[t+256] = f2b((v1-mean)*rs*w[t+256] + b[t+256]);
    yr[t+512] = f2b((v2-mean)*rs*w[t+512] + b[t+512]);
}

// ---------------- loss ----------------
__global__ void loss_rows_k(const float* __restrict__ logits, const int* __restrict__ tgt,
                            float* __restrict__ row_loss)
{
    int row = blockIdx.x;
    const float* lr = logits + (long)row*Vz;
    int t = threadIdx.x;
    __shared__ float sm[256];
    float mx = -3.4e38f;
    for (int c = t; c < Vz; c += 256) mx = fmaxf(mx, lr[c]);
    sm[t] = mx; __syncthreads();
    for (int k = 128; k > 0; k >>= 1) { if (t < k) sm[t] = fmaxf(sm[t], sm[t+k]); __syncthreads(); }
    float m = sm[0]; __syncthreads();
    float s = 0.f;
    for (int c = t; c < Vz; c += 256) s += expf(lr[c]-m);
    sm[t] = s; __syncthreads();
    for (int k = 128; k > 0; k >>= 1) { if (t < k) sm[t] += sm[t+k]; __syncthreads(); }
    if (t == 0) {
        float logZ = m + logf(sm[0]);
        row_loss[row] = logZ - lr[tgt[row]];
    }
}

__global__ void loss_reduce_k(const float* __restrict__ row_loss, float* __restrict__ out)
{
    __shared__ float sm[256];
    int t = threadIdx.x;
    float s = 0.f;
    for (int i = t; i < BTz; i += 256) s += row_loss[i];
    sm[t] = s; __syncthreads();
    for (int k = 128; k > 0; k >>= 1) { if (t < k) sm[t] += sm[t+k]; __syncthreads(); }
    if (t == 0) out[0] = sm[0] * (1.0f/BTz);
}

// ---------------- host ----------------
extern "C" void kernel_launch(void* const* d_in, const int* in_sizes, int n_in,
                              void* d_out, int out_size, void* d_ws, size_t ws_size,
                              hipStream_t stream)
{
    const int*   idx     = (const int*)  d_in[0];
    const int*   tgt     = (const int*)  d_in[1];
    const float* tok_emb = (const float*)d_in[2];
    const float* pos_emb = (const float*)d_in[3];
    const float* ln1_w   = (const float*)d_in[4];
    const float* ln1_b   = (const float*)d_in[5];
    const float* wq      = (const float*)d_in[6];
    const float* wk      = (const float*)d_in[7];
    const float* wv      = (const float*)d_in[8];
    const float* wo      = (const float*)d_in[9];
    const float* bo      = (const float*)d_in[10];
    const float* ln2_w   = (const float*)d_in[11];
    const float* ln2_b   = (const float*)d_in[12];
    const float* w1      = (const float*)d_in[13];
    const float* b1      = (const float*)d_in[14];
    const float* w2      = (const float*)d_in[15];
    const float* b2      = (const float*)d_in[16];
    const float* lnf_w   = (const float*)d_in[17];
    const float* lnf_b   = (const float*)d_in[18];
    const float* lm_w    = (const float*)d_in[19];
    const float* lm_b    = (const float*)d_in[20];

    float* logits = (float*)d_out;
    float* loss   = logits + (long)BTz*Vz;

    // ws layout (~49 MB total)
    float* x     = (float*)d_ws;
    float* rloss = x + (long)BTz*Dz;
    short* h     = (short*)(rloss + BTz);
    short* qkvb  = h    + (long)BTz*Dz;
    short* attb  = qkvb + (long)BTz*2304;
    short* midb  = attb + (long)BTz*Dz;
    short* wbuf  = midb + (long)BTz*DFz;
    short* qkvw  = wbuf;                       // [2304][768]
    short* w1t   = wbuf + 2304*768;            // [3072][768]
    short* w2t   = w1t  + 3072*768;            // [768][3072]
    short* wot   = w2t  + 768*3072;            // [768][768]

    embed_k<<<dim3((BTz*(Dz/4) + 255)/256), 256, 0, stream>>>(idx, tok_emb, pos_emb, x);

    for (int l = 0; l < Lz; l++) {
        const long wsz = (long)Dz*Dz;
        tconv_k<<<dim3(24,24), 256, 0, stream>>>(wq + l*wsz, qkvw,            Dz, Dz, Dz);
        tconv_k<<<dim3(24,24), 256, 0, stream>>>(wk + l*wsz, qkvw + 768*768,  Dz, Dz, Dz);
        tconv_k<<<dim3(24,24), 256, 0, stream>>>(wv + l*wsz, qkvw + 1536*768, Dz, Dz, Dz);
        tconv_k<<<dim3(24,24), 256, 0, stream>>>(wo + l*wsz, wot, Dz, Dz, Dz);
        tconv_k<<<dim3(96,24), 256, 0, stream>>>(w1 + (long)l*Dz*DFz, w1t, Dz, DFz, DFz);
        tconv_k<<<dim3(24,96), 256, 0, stream>>>(w2 + (long)l*Dz*DFz, w2t, DFz, Dz, Dz);

        ln_k<<<BTz, 256, 0, stream>>>(x, ln1_w + l*Dz, ln1_b + l*Dz, h);
        gemm2<128,0,true ><<<dim3(18,16), 256, 0, stream>>>(h, qkvw, nullptr, nullptr, qkvb, Dz, 2304);
        attn_k<<<dim3(Tz/64, Hz, Bz), 256, 0, stream>>>(qkvb, attb);
        gemm2<64, 2,false><<<dim3(6,32),  256, 0, stream>>>(attb, wot, bo + l*Dz, x, x, Dz, Dz);
        ln_k<<<BTz, 256, 0, stream>>>(x, ln2_w + l*Dz, ln2_b + l*Dz, h);
        gemm2<128,3,true ><<<dim3(24,16), 256, 0, stream>>>(h, w1t, b1 + l*DFz, nullptr, midb, Dz, DFz);
        gemm2<64, 2,false><<<dim3(6,32),  256, 0, stream>>>(midb, w2t, b2 + l*Dz, x, x, DFz, Dz);
    }

    ln_k<<<BTz, 256, 0, stream>>>(x, lnf_w, lnf_b, h);
    for (int c = 0; c < Vz; c += 8192) {
        int cn = (Vz - c < 8192) ? (Vz - c) : 8192;
        tconv_k<<<dim3(cn/32, 24), 256, 0, stream>>>(lm_w + c, wbuf, Dz, cn, Vz);
        gemm2<128,1,false><<<dim3(cn/128, 16), 256, 0, stream>>>(h, wbuf, lm_b + c, nullptr, logits + c, Dz, Vz);
    }

    loss_rows_k<<<BTz, 256, 0, stream>>>(logits, tgt, rloss);
    loss_reduce_k<<<1, 256, 0, stream>>>(rloss, loss);
}